// Round 9
// baseline (569.968 us; speedup 1.0000x reference)
//
#include <hip/hip_runtime.h>

#define NT 1024
#define SEQ_LEN 8192

static __device__ __forceinline__ float2 f2(float x, float y){ return make_float2(x,y); }
static __device__ __forceinline__ float2 cadd(float2 a, float2 b){ return f2(a.x+b.x, a.y+b.y); }
static __device__ __forceinline__ float2 csub(float2 a, float2 b){ return f2(a.x-b.x, a.y-b.y); }
static __device__ __forceinline__ float2 cmul(float2 a, float2 b){ return f2(a.x*b.x-a.y*b.y, a.x*b.y+a.y*b.x); }
static __device__ __forceinline__ float2 cmulc(float2 a, float2 b){ return f2(a.x*b.x+a.y*b.y, a.y*b.x-a.x*b.y); } // a*conj(b)
static __device__ __forceinline__ float2 mul_mi(float2 a){ return f2(a.y, -a.x); }  // a * (-i)
static __device__ __forceinline__ float2 mul_pi(float2 a){ return f2(-a.y, a.x); }  // a * (+i)
static __device__ __forceinline__ int swz(int e){ return e ^ ((e>>4)&15) ^ ((e>>8)&15); }
static __device__ __forceinline__ int rev13(int v){ return (int)(__brev((unsigned)v) >> 19); }

// ---------------- MLP: h3[j][16] = sin-MLP(z[j]) ----------------
__global__ void hyena_mlp(const float* __restrict__ z,
                          const float* __restrict__ W1, const float* __restrict__ b1,
                          const float* __restrict__ W2, const float* __restrict__ b2,
                          const float* __restrict__ W3, const float* __restrict__ b3,
                          const float* __restrict__ freq,
                          float* __restrict__ h3) {
    int j = blockIdx.x * blockDim.x + threadIdx.x;
    if (j >= SEQ_LEN) return;
    float z0 = z[3*j+0], z1 = z[3*j+1], z2 = z[3*j+2];
    float ha[16], hb[16];
#pragma unroll
    for (int o = 0; o < 16; ++o) {
        float acc = b1[o] + z0*W1[o] + z1*W1[16+o] + z2*W1[32+o];
        ha[o] = sinf(freq[o] * acc);
    }
#pragma unroll
    for (int p = 0; p < 16; ++p) {
        float acc = b2[p];
#pragma unroll
        for (int o = 0; o < 16; ++o) acc += ha[o] * W2[o*16+p];
        hb[p] = sinf(freq[p] * acc);
    }
#pragma unroll
    for (int q = 0; q < 16; ++q) {
        float acc = b3[q];
#pragma unroll
        for (int o = 0; o < 16; ++o) acc += hb[o] * W3[o*16+q];
        h3[j*16+q] = sinf(freq[q] * acc);
    }
}

// ---- proj: k[d][j] = (h3[j]·Wout[:,d]) * exp(-t_j*|delta_d|), row-major [1024][8192] ----
#define PJ 128
__global__ void hyena_proj(const float* __restrict__ h3, const float* __restrict__ Wout,
                           float* __restrict__ krows) {
    __shared__ float sW[16][1024];     // 64 KB
    __shared__ float sh[PJ][17];
    const int t = threadIdx.x;         // 256
    const int jb = blockIdx.x * PJ;
    for (int i = t; i < 16*1024; i += 256) sW[i>>10][i&1023] = Wout[i];
    for (int i = t; i < PJ*16; i += 256)   sh[i>>4][i&15]    = h3[(size_t)(jb + (i>>4))*16 + (i&15)];
    __syncthreads();
    const float dmin = -3.0701134573253941f;   // log(0.01)/1.5
    const float dmax = -15.350567286626971f;   // log(0.01)/0.3
    const int jloc = t & 127;
    const int dloc = t >> 7;
    const float tj = (float)(jb + jloc) * (1.0f/8191.0f);
#pragma unroll 1
    for (int db = 0; db < 1024; db += 2) {
        int d = db + dloc;
        float absd = fabsf(dmin + (dmax - dmin) * ((float)d * (1.0f/1023.0f)));
        float acc = 0.f;
#pragma unroll
        for (int o = 0; o < 16; ++o) acc += sh[jloc][o] * sW[o][d];
        krows[(size_t)d*SEQ_LEN + jb + jloc] = acc * __expf(-tj * absd);
    }
}

// ------ radix-8 (3 radix-2 stages) register butterflies ------
// DIF pass on stages m+2,m+1,m (descending stride): elements r[k] = c[B + k*2^m].
// Base twiddle wd = W_{8*2^m}^{g mod 2^m}; stage twiddles: A: wd*W8^k, B: wd^2*W4^k, C: wd^4.
static __device__ __forceinline__ void dif3(float2 r[8], float2 wd){
    const float2 c2 = f2(0.7071067811865476f,-0.7071067811865476f);  // e^{-i pi/4}
    float2 wd2 = cmul(wd,wd), wd4 = cmul(wd2,wd2);
    float2 wc2 = cmul(wd,c2);
    // stage A (stride 4): twiddles wd * {1, c2, -i, -i*c2}
    { float2 u=r[0], v=r[4]; r[0]=cadd(u,v); r[4]=cmul(csub(u,v), wd); }
    { float2 u=r[1], v=r[5]; r[1]=cadd(u,v); r[5]=cmul(csub(u,v), wc2); }
    { float2 u=r[2], v=r[6]; r[2]=cadd(u,v); r[6]=mul_mi(cmul(csub(u,v), wd)); }
    { float2 u=r[3], v=r[7]; r[3]=cadd(u,v); r[7]=mul_mi(cmul(csub(u,v), wc2)); }
    // stage B (stride 2): wd2, -i*wd2
    { float2 u=r[0], v=r[2]; r[0]=cadd(u,v); r[2]=cmul(csub(u,v), wd2); }
    { float2 u=r[1], v=r[3]; r[1]=cadd(u,v); r[3]=mul_mi(cmul(csub(u,v), wd2)); }
    { float2 u=r[4], v=r[6]; r[4]=cadd(u,v); r[6]=cmul(csub(u,v), wd2); }
    { float2 u=r[5], v=r[7]; r[5]=cadd(u,v); r[7]=mul_mi(cmul(csub(u,v), wd2)); }
    // stage C (stride 1): wd4
    { float2 u=r[0], v=r[1]; r[0]=cadd(u,v); r[1]=cmul(csub(u,v), wd4); }
    { float2 u=r[2], v=r[3]; r[2]=cadd(u,v); r[3]=cmul(csub(u,v), wd4); }
    { float2 u=r[4], v=r[5]; r[4]=cadd(u,v); r[5]=cmul(csub(u,v), wd4); }
    { float2 u=r[6], v=r[7]; r[6]=cadd(u,v); r[7]=cmul(csub(u,v), wd4); }
}
// DIT inverse (ascending): conj twiddles, mirror order.
static __device__ __forceinline__ void dit3(float2 r[8], float2 wd){
    const float2 c2 = f2(0.7071067811865476f,-0.7071067811865476f);
    float2 wd2 = cmul(wd,wd), wd4 = cmul(wd2,wd2);
    float2 wc2 = cmul(wd,c2);
    // stage C' (stride 1): conj(wd4)
    { float2 u=r[0]; float2 t=cmulc(r[1], wd4); r[0]=cadd(u,t); r[1]=csub(u,t); }
    { float2 u=r[2]; float2 t=cmulc(r[3], wd4); r[2]=cadd(u,t); r[3]=csub(u,t); }
    { float2 u=r[4]; float2 t=cmulc(r[5], wd4); r[4]=cadd(u,t); r[5]=csub(u,t); }
    { float2 u=r[6]; float2 t=cmulc(r[7], wd4); r[6]=cadd(u,t); r[7]=csub(u,t); }
    // stage B' (stride 2): conj(wd2), +i*conj(wd2)
    { float2 u=r[0]; float2 t=cmulc(r[2], wd2);         r[0]=cadd(u,t); r[2]=csub(u,t); }
    { float2 u=r[1]; float2 t=mul_pi(cmulc(r[3], wd2)); r[1]=cadd(u,t); r[3]=csub(u,t); }
    { float2 u=r[4]; float2 t=cmulc(r[6], wd2);         r[4]=cadd(u,t); r[6]=csub(u,t); }
    { float2 u=r[5]; float2 t=mul_pi(cmulc(r[7], wd2)); r[5]=cadd(u,t); r[7]=csub(u,t); }
    // stage A' (stride 4): conj(wd*W8^k)
    { float2 u=r[0]; float2 t=cmulc(r[4], wd);          r[0]=cadd(u,t); r[4]=csub(u,t); }
    { float2 u=r[1]; float2 t=cmulc(r[5], wc2);         r[1]=cadd(u,t); r[5]=csub(u,t); }
    { float2 u=r[2]; float2 t=mul_pi(cmulc(r[6], wd));  r[2]=cadd(u,t); r[6]=csub(u,t); }
    { float2 u=r[3]; float2 t=mul_pi(cmulc(r[7], wc2)); r[3]=cadd(u,t); r[7]=csub(u,t); }
}

// aligned pair access (positions p even; swz may flip parity, so select)
static __device__ __forceinline__ void readpair(const float2* cv, int p, float2& e0, float2& e1){
    int sp = swz(p);
    float4 q = *(const float4*)&cv[sp & ~1];
    float2 lo = f2(q.x,q.y), hi = f2(q.z,q.w);
    if (sp & 1) { e0 = hi; e1 = lo; } else { e0 = lo; e1 = hi; }
}
static __device__ __forceinline__ void writepair(float2* cv, int p, float2 e0, float2 e1){
    int sp = swz(p);
    float4 q;
    if (sp & 1) q = make_float4(e1.x,e1.y,e0.x,e0.y);
    else        q = make_float4(e0.x,e0.y,e1.x,e1.y);
    *(float4*)&cv[sp & ~1] = q;
}

static __device__ __forceinline__ float2 getw(const float2* T1, const float2* T2, int k){
    return cmul(T1[k>>6], T2[k&63]);   // e^{-i pi k / 8192}
}
static __device__ __forceinline__ float4 kpack(float2 Ck, float2 Cm, float2 w, float bds){
    const float s = 1.0f/16384.0f;
    float2 A  = f2(0.5f*(Ck.x+Cm.x), 0.5f*(Ck.y-Cm.y));
    float2 Bc = f2(0.5f*(Ck.x-Cm.x), 0.5f*(Ck.y+Cm.y));
    float2 B  = f2(Bc.y, -Bc.x);
    float2 wB = cmul(w, B);
    return make_float4((A.x+wB.x)*s + bds, (A.y+wB.y)*s,
                       (A.x-wB.x)*s + bds, -((A.y-wB.y)*s));
}
static __device__ __forceinline__ void pwmul(float2 Ck, float2 Cm, float4 Kp, float2 w,
                                             float2& Dk, float2& Dm){
    float2 A  = f2(0.5f*(Ck.x+Cm.x), 0.5f*(Ck.y-Cm.y));
    float2 Bc = f2(0.5f*(Ck.x-Cm.x), 0.5f*(Ck.y+Cm.y));
    float2 B  = f2(Bc.y, -Bc.x);
    float2 wB = cmul(w, B);
    float2 Xk = f2(A.x+wB.x, A.y+wB.y);
    float2 Xm = f2(A.x-wB.x, -(A.y-wB.y));
    float2 Yk = cmul(Xk, f2(Kp.x,Kp.y));
    float2 Ym = cmul(Xm, f2(Kp.z,Kp.w));
    float2 A2 = f2(Yk.x+Ym.x, Yk.y-Ym.y);
    float2 Bt = f2(Yk.x-Ym.x, Yk.y+Ym.y);
    float2 B2 = cmulc(Bt, w);
    Dk = f2(A2.x - B2.y, A2.y + B2.x);
    Dm = f2(A2.x + B2.y, B2.x - A2.y);
}

// LDS (f2 units): cv 8192 | tab 1024 | T1 64 | T2 64 | Kex 2 (+2) | KA 4096 | KB 4096
// = 17540 f2 = 140320 B -> 1 block/CU, 16 waves/CU (4 waves/SIMD).
#define SMEM_BYTES (17540 * 8)

// NT=1024, r[8]: per-thread live set ~70-80 VGPRs — fits the 128 budget the
// compiler insists on for big blocks (rounds 3-8: VGPR pinned at 128, spills).
template<bool USE_K>
__global__ __launch_bounds__(NT, 1)
void hyena_conv(const float* __restrict__ h3g, const float* __restrict__ Wout,
                const float* __restrict__ krows,
                const float* __restrict__ x, const float* __restrict__ bias,
                float* __restrict__ out) {
    extern __shared__ float2 smem[];
    float2* cv  = smem;                 // 8192
    float2* tab = cv + 8192;            // 1024: e^{-i pi p/4096}
    float2* T1  = tab + 1024;           // 64:  e^{-i pi h/128}
    float2* T2  = T1 + 64;              // 64:  e^{-i pi l/8192}
    float2* Kex = T2 + 64;              // 2:   K-pack for f=2048
    float4* KA  = (float4*)(Kex + 4);   // 2048 f4 (16B-aligned: 74784 % 16 == 0)
    float4* KB  = KA + 2048;            // 2048 f4
    const int t = threadIdx.x;
    const int d = blockIdx.x;
    const float PI = 3.14159265358979323846f;

    { float s_,c_; sincosf((PI/4096.0f)*(float)t, &s_, &c_); tab[t] = f2(c_, -s_); }
    if (t < 64)       { float s_,c_; sincosf((PI/128.0f)*(float)t, &s_,&c_); T1[t] = f2(c_,-s_); }
    else if (t < 128) { int l=t-64; float s_,c_; sincosf((PI/8192.0f)*(float)l,&s_,&c_); T2[l] = f2(c_,-s_); }
    __syncthreads();

    // pass A: stages 12..10, elements t + 1024k,            wd = W_8192^t
    // pass B: stages  9..7,  elements bB + 128k,            wd = W_1024^(t&127)
    // pass C: stages  6..4,  elements bC + 16k,             wd = W_128^(t&15)
    // pass D: stages  3..1,  elements bD + 2k,              wd = W_16^(t&1)
    const float2 wdA = tab[t];
    const float2 wdB = tab[(t&127)<<3];
    const float2 wdC = tab[(t&15)<<6];
    const float2 wdD = tab[(t&1)<<9];
    const int bB = ((t>>7)<<10) | (t&127);
    const int bC = ((t>>4)<<7)  | (t&15);
    const int bD = ((t>>1)<<4)  | (t&1);

    const float bds = bias[d] * (1.0f/16384.0f);

    float2 r[8];
    // ---- filter row -> spectrum K in LDS ----
    if (USE_K) {
        const float2* kr = (const float2*)(krows + (size_t)d * SEQ_LEN);
#pragma unroll
        for (int k = 0; k < 4; ++k) r[k] = kr[t + 1024*k];
    } else {
        const float dmin = -3.0701134573253941f;
        const float dmax = -15.350567286626971f;
        const float absd = fabsf(dmin + (dmax - dmin) * ((float)d * (1.0f/1023.0f)));
        float wcol[16];
#pragma unroll
        for (int o = 0; o < 16; ++o) wcol[o] = Wout[o*1024 + d];
#pragma unroll
        for (int k = 0; k < 4; ++k) {
            int e = t + 1024*k;
            const float4* h4 = (const float4*)(h3g + (size_t)(2*e)*16);
            float a0 = 0.f, a1 = 0.f;
#pragma unroll
            for (int v4 = 0; v4 < 4; ++v4) {
                float4 q0 = h4[v4], q1 = h4[4+v4];
                a0 += q0.x*wcol[4*v4] + q0.y*wcol[4*v4+1] + q0.z*wcol[4*v4+2] + q0.w*wcol[4*v4+3];
                a1 += q1.x*wcol[4*v4] + q1.y*wcol[4*v4+1] + q1.z*wcol[4*v4+2] + q1.w*wcol[4*v4+3];
            }
            float ta = (float)(2*e)   * (1.0f/8191.0f);
            float tb = (float)(2*e+1) * (1.0f/8191.0f);
            r[k] = f2(a0 * __expf(-ta*absd), a1 * __expf(-tb*absd));
        }
    }
#pragma unroll
    for (int k = 4; k < 8; ++k) r[k] = f2(0.f, 0.f);

    dif3(r, wdA);
#pragma unroll
    for (int k = 0; k < 8; ++k) cv[swz(t + 1024*k)] = r[k];
    __syncthreads();
#pragma unroll
    for (int k = 0; k < 8; ++k) r[k] = cv[swz(bB + 128*k)];
    dif3(r, wdB);
#pragma unroll
    for (int k = 0; k < 8; ++k) cv[swz(bB + 128*k)] = r[k];
    __syncthreads();
#pragma unroll
    for (int k = 0; k < 8; ++k) r[k] = cv[swz(bC + 16*k)];
    dif3(r, wdC);
#pragma unroll
    for (int k = 0; k < 8; ++k) cv[swz(bC + 16*k)] = r[k];
    __syncthreads();
#pragma unroll
    for (int k = 0; k < 8; ++k) r[k] = cv[swz(bD + 2*k)];
    dif3(r, wdD);
#pragma unroll
    for (int k = 0; k < 8; ++k) cv[swz(bD + 2*k)] = r[k];
    __syncthreads();

    // unpack rfft(K) -> packed spectrum in LDS (index = f)
#pragma unroll 1
    for (int q = 0; q < 2; ++q) {
        int f = t + 1024*q;
        if (f == 0) {
            float2 a0,a1; readpair(cv, 0, a0, a1);
            float2 C0 = cadd(a0,a1), C4 = csub(a0,a1);   // fwd stage 0
            const float s = 1.0f/16384.0f;
            KA[0] = make_float4((C0.x+C0.y)*s + bds, (C0.x-C0.y)*s + bds, C4.x*s + bds, -C4.y*s);
            KB[0] = make_float4(0.f,0.f,0.f,0.f);
        } else {
            int g = 4096 - f;
            float2 a0,a1,b0,b1;
            readpair(cv, rev13(f), a0, a1);
            readpair(cv, rev13(g), b0, b1);
            float2 Cf=cadd(a0,a1), Cf4=csub(a0,a1), Cg=cadd(b0,b1), Cg4=csub(b0,b1);
            KA[f] = kpack(Cf, Cg4, getw(T1,T2,f), bds);
            KB[f] = kpack(Cg, Cf4, getw(T1,T2,g), bds);
        }
    }
    if (t == 0) {
        float2 b0,b1; readpair(cv, 2, b0, b1);   // rev13(2048) = 2
        float4 K20 = kpack(cadd(b0,b1), csub(b0,b1), getw(T1,T2,2048), bds);
        Kex[0] = f2(K20.x, K20.y);
        Kex[1] = f2(K20.z, K20.w);
    }
    __syncthreads();

    // ---- batches ----
#pragma unroll 1
    for (int b = 0; b < 4; ++b) {
        const float2* xr = (const float2*)(x + ((size_t)b*1024 + d)*SEQ_LEN);
        float2* yr = (float2*)(out + ((size_t)b*1024 + d)*SEQ_LEN);

        // F1: global -> regs, pass A, -> LDS
#pragma unroll
        for (int k = 0; k < 4; ++k) r[k] = xr[t + 1024*k];
#pragma unroll
        for (int k = 4; k < 8; ++k) r[k] = f2(0.f,0.f);
        dif3(r, wdA);
#pragma unroll
        for (int k = 0; k < 8; ++k) cv[swz(t + 1024*k)] = r[k];
        __syncthreads();
        // F2: pass B
#pragma unroll
        for (int k = 0; k < 8; ++k) r[k] = cv[swz(bB + 128*k)];
        dif3(r, wdB);
#pragma unroll
        for (int k = 0; k < 8; ++k) cv[swz(bB + 128*k)] = r[k];
        __syncthreads();
        // F3: pass C
#pragma unroll
        for (int k = 0; k < 8; ++k) r[k] = cv[swz(bC + 16*k)];
        dif3(r, wdC);
#pragma unroll
        for (int k = 0; k < 8; ++k) cv[swz(bC + 16*k)] = r[k];
        __syncthreads();
        // F4: pass D
#pragma unroll
        for (int k = 0; k < 8; ++k) r[k] = cv[swz(bD + 2*k)];
        dif3(r, wdD);
#pragma unroll
        for (int k = 0; k < 8; ++k) cv[swz(bD + 2*k)] = r[k];
        __syncthreads();

        // FUSED: fwd stage 0 + rfft-unpack * K + repack + inv stage 0
#pragma unroll 1
        for (int q = 0; q < 2; ++q) {
            int f = t + 1024*q;
            float4 Kpa = KA[f];
            if (f == 0) {
                float2 a0,a1; readpair(cv, 0, a0, a1);
                float2 C0 = cadd(a0,a1), C4 = csub(a0,a1);
                float R0 = C0.x + C0.y, RN = C0.x - C0.y;
                float Y0 = R0 * Kpa.x, YN = RN * Kpa.y;
                float2 D0 = f2(Y0+YN, Y0-YN);
                float2 Y4 = cmul(f2(C4.x,-C4.y), f2(Kpa.z, Kpa.w));
                float2 D4 = f2(2.f*Y4.x, -2.f*Y4.y);
                writepair(cv, 0, cadd(D0,D4), csub(D0,D4));
            } else {
                float4 Kpb = KB[f];
                int g = 4096 - f;
                int p1 = rev13(f), p2 = rev13(g);
                float2 a0,a1,b0,b1;
                readpair(cv, p1, a0, a1);
                readpair(cv, p2, b0, b1);
                float2 Cf=cadd(a0,a1), Cf4=csub(a0,a1), Cg=cadd(b0,b1), Cg4=csub(b0,b1);
                float2 Df,Dg4,Dg,Df4;
                pwmul(Cf, Cg4, Kpa, getw(T1,T2,f), Df, Dg4);
                pwmul(Cg, Cf4, Kpb, getw(T1,T2,g), Dg, Df4);
                writepair(cv, p1, cadd(Df,Df4), csub(Df,Df4));
                writepair(cv, p2, cadd(Dg,Dg4), csub(Dg,Dg4));
            }
        }
        if (t == 0) {   // f = 2048 self-paired quad at positions (2,3)
            float4 K20 = make_float4(Kex[0].x, Kex[0].y, Kex[1].x, Kex[1].y);
            float2 b0,b1; readpair(cv, 2, b0, b1);
            float2 Ck=cadd(b0,b1), Cm=csub(b0,b1), Dk, Dm;
            pwmul(Ck, Cm, K20, getw(T1,T2,2048), Dk, Dm);
            writepair(cv, 2, cadd(Dk,Dm), csub(Dk,Dm));
        }
        __syncthreads();

        // I4: pass D' (stages 1..3)
#pragma unroll
        for (int k = 0; k < 8; ++k) r[k] = cv[swz(bD + 2*k)];
        dit3(r, wdD);
#pragma unroll
        for (int k = 0; k < 8; ++k) cv[swz(bD + 2*k)] = r[k];
        __syncthreads();
        // I3: pass C' (stages 4..6)
#pragma unroll
        for (int k = 0; k < 8; ++k) r[k] = cv[swz(bC + 16*k)];
        dit3(r, wdC);
#pragma unroll
        for (int k = 0; k < 8; ++k) cv[swz(bC + 16*k)] = r[k];
        __syncthreads();
        // I2: pass B' (stages 7..9)
#pragma unroll
        for (int k = 0; k < 8; ++k) r[k] = cv[swz(bB + 128*k)];
        dit3(r, wdB);
#pragma unroll
        for (int k = 0; k < 8; ++k) cv[swz(bB + 128*k)] = r[k];
        __syncthreads();
        // I1: pass A' (stages 10..12), first half straight to global
#pragma unroll
        for (int k = 0; k < 8; ++k) r[k] = cv[swz(t + 1024*k)];
        dit3(r, wdA);
#pragma unroll
        for (int k = 0; k < 4; ++k) yr[t + 1024*k] = r[k];
        __syncthreads();
    }
}

extern "C" void kernel_launch(void* const* d_in, const int* in_sizes, int n_in,
                              void* d_out, int out_size, void* d_ws, size_t ws_size,
                              hipStream_t stream) {
    const float* x    = (const float*)d_in[0];
    const float* z    = (const float*)d_in[2];
    const float* W1   = (const float*)d_in[3];
    const float* b1   = (const float*)d_in[4];
    const float* W2   = (const float*)d_in[5];
    const float* b2   = (const float*)d_in[6];
    const float* W3   = (const float*)d_in[7];
    const float* b3   = (const float*)d_in[8];
    const float* Wout = (const float*)d_in[9];
    const float* freq = (const float*)d_in[10];
    const float* bias = (const float*)d_in[11];
    float* out = (float*)d_out;
    float* h3  = (float*)d_ws;                                  // 512 KB
    float* krows = (float*)((char*)d_ws + 512*1024);            // 32 MB

    const size_t need = 512*1024 + (size_t)32*1024*1024;
    const bool use_k = ws_size >= need;

    hipLaunchKernelGGL(hyena_mlp, dim3(SEQ_LEN/256), dim3(256), 0, stream,
                       z, W1, b1, W2, b2, W3, b3, freq, h3);

    static bool attr_set = false;
    if (!attr_set) {
        (void)hipFuncSetAttribute((const void*)hyena_conv<true>,
                                  hipFuncAttributeMaxDynamicSharedMemorySize, SMEM_BYTES);
        (void)hipFuncSetAttribute((const void*)hyena_conv<false>,
                                  hipFuncAttributeMaxDynamicSharedMemorySize, SMEM_BYTES);
        attr_set = true;
    }

    if (use_k) {
        hipLaunchKernelGGL(hyena_proj, dim3(SEQ_LEN/PJ), dim3(256), 0, stream,
                           h3, Wout, krows);
        hipLaunchKernelGGL(hyena_conv<true>, dim3(1024), dim3(NT), SMEM_BYTES, stream,
                           h3, Wout, krows, x, bias, out);
    } else {
        hipLaunchKernelGGL(hyena_conv<false>, dim3(1024), dim3(NT), SMEM_BYTES, stream,
                           h3, Wout, krows, x, bias, out);
    }
}

// Round 10
// 356.921 us; speedup vs baseline: 1.5969x; 1.5969x over previous
//
#include <hip/hip_runtime.h>

#define NT 512
#define SEQ_LEN 8192

static __device__ __forceinline__ float2 f2(float x, float y){ return make_float2(x,y); }
static __device__ __forceinline__ float2 cadd(float2 a, float2 b){ return f2(a.x+b.x, a.y+b.y); }
static __device__ __forceinline__ float2 csub(float2 a, float2 b){ return f2(a.x-b.x, a.y-b.y); }
static __device__ __forceinline__ float2 cmul(float2 a, float2 b){ return f2(a.x*b.x-a.y*b.y, a.x*b.y+a.y*b.x); }
static __device__ __forceinline__ float2 cmulc(float2 a, float2 b){ return f2(a.x*b.x+a.y*b.y, a.y*b.x-a.x*b.y); } // a*conj(b)
static __device__ __forceinline__ float2 mul_mi(float2 a){ return f2(a.y, -a.x); }  // a * (-i)
static __device__ __forceinline__ float2 mul_pi(float2 a){ return f2(-a.y, a.x); }  // a * (+i)
static __device__ __forceinline__ int swz(int e){ return e ^ ((e>>4)&15) ^ ((e>>8)&15); }
static __device__ __forceinline__ int rev13(int v){ return (int)(__brev((unsigned)v) >> 19); }

// ---------------- MLP: h3[j][16] = sin-MLP(z[j]) ----------------
__global__ void hyena_mlp(const float* __restrict__ z,
                          const float* __restrict__ W1, const float* __restrict__ b1,
                          const float* __restrict__ W2, const float* __restrict__ b2,
                          const float* __restrict__ W3, const float* __restrict__ b3,
                          const float* __restrict__ freq,
                          float* __restrict__ h3) {
    int j = blockIdx.x * blockDim.x + threadIdx.x;
    if (j >= SEQ_LEN) return;
    float z0 = z[3*j+0], z1 = z[3*j+1], z2 = z[3*j+2];
    float ha[16], hb[16];
#pragma unroll
    for (int o = 0; o < 16; ++o) {
        float acc = b1[o] + z0*W1[o] + z1*W1[16+o] + z2*W1[32+o];
        ha[o] = sinf(freq[o] * acc);
    }
#pragma unroll
    for (int p = 0; p < 16; ++p) {
        float acc = b2[p];
#pragma unroll
        for (int o = 0; o < 16; ++o) acc += ha[o] * W2[o*16+p];
        hb[p] = sinf(freq[p] * acc);
    }
#pragma unroll
    for (int q = 0; q < 16; ++q) {
        float acc = b3[q];
#pragma unroll
        for (int o = 0; o < 16; ++o) acc += hb[o] * W3[o*16+q];
        h3[j*16+q] = sinf(freq[q] * acc);
    }
}

// ---- proj: k[d][j] = (h3[j]·Wout[:,d]) * exp(-t_j*|delta_d|), row-major [1024][8192] ----
#define PJ 128
__global__ void hyena_proj(const float* __restrict__ h3, const float* __restrict__ Wout,
                           float* __restrict__ krows) {
    __shared__ float sW[16][1024];     // 64 KB
    __shared__ float sh[PJ][17];
    const int t = threadIdx.x;         // 256
    const int jb = blockIdx.x * PJ;
    for (int i = t; i < 16*1024; i += 256) sW[i>>10][i&1023] = Wout[i];
    for (int i = t; i < PJ*16; i += 256)   sh[i>>4][i&15]    = h3[(size_t)(jb + (i>>4))*16 + (i&15)];
    __syncthreads();
    const float dmin = -3.0701134573253941f;   // log(0.01)/1.5
    const float dmax = -15.350567286626971f;   // log(0.01)/0.3
    const int jloc = t & 127;
    const int dloc = t >> 7;
    const float tj = (float)(jb + jloc) * (1.0f/8191.0f);
#pragma unroll 1
    for (int db = 0; db < 1024; db += 2) {
        int d = db + dloc;
        float absd = fabsf(dmin + (dmax - dmin) * ((float)d * (1.0f/1023.0f)));
        float acc = 0.f;
#pragma unroll
        for (int o = 0; o < 16; ++o) acc += sh[jloc][o] * sW[o][d];
        krows[(size_t)d*SEQ_LEN + jb + jloc] = acc * __expf(-tj * absd);
    }
}

// ------ radix-8 (3 radix-2 stages) register butterflies (verified in round 9) ------
static __device__ __forceinline__ void dif3(float2 r[8], float2 wd){
    const float2 c2 = f2(0.7071067811865476f,-0.7071067811865476f);  // e^{-i pi/4}
    float2 wd2 = cmul(wd,wd), wd4 = cmul(wd2,wd2);
    float2 wc2 = cmul(wd,c2);
    { float2 u=r[0], v=r[4]; r[0]=cadd(u,v); r[4]=cmul(csub(u,v), wd); }
    { float2 u=r[1], v=r[5]; r[1]=cadd(u,v); r[5]=cmul(csub(u,v), wc2); }
    { float2 u=r[2], v=r[6]; r[2]=cadd(u,v); r[6]=mul_mi(cmul(csub(u,v), wd)); }
    { float2 u=r[3], v=r[7]; r[3]=cadd(u,v); r[7]=mul_mi(cmul(csub(u,v), wc2)); }
    { float2 u=r[0], v=r[2]; r[0]=cadd(u,v); r[2]=cmul(csub(u,v), wd2); }
    { float2 u=r[1], v=r[3]; r[1]=cadd(u,v); r[3]=mul_mi(cmul(csub(u,v), wd2)); }
    { float2 u=r[4], v=r[6]; r[4]=cadd(u,v); r[6]=cmul(csub(u,v), wd2); }
    { float2 u=r[5], v=r[7]; r[5]=cadd(u,v); r[7]=mul_mi(cmul(csub(u,v), wd2)); }
    { float2 u=r[0], v=r[1]; r[0]=cadd(u,v); r[1]=cmul(csub(u,v), wd4); }
    { float2 u=r[2], v=r[3]; r[2]=cadd(u,v); r[3]=cmul(csub(u,v), wd4); }
    { float2 u=r[4], v=r[5]; r[4]=cadd(u,v); r[5]=cmul(csub(u,v), wd4); }
    { float2 u=r[6], v=r[7]; r[6]=cadd(u,v); r[7]=cmul(csub(u,v), wd4); }
}
static __device__ __forceinline__ void dit3(float2 r[8], float2 wd){
    const float2 c2 = f2(0.7071067811865476f,-0.7071067811865476f);
    float2 wd2 = cmul(wd,wd), wd4 = cmul(wd2,wd2);
    float2 wc2 = cmul(wd,c2);
    { float2 u=r[0]; float2 t=cmulc(r[1], wd4); r[0]=cadd(u,t); r[1]=csub(u,t); }
    { float2 u=r[2]; float2 t=cmulc(r[3], wd4); r[2]=cadd(u,t); r[3]=csub(u,t); }
    { float2 u=r[4]; float2 t=cmulc(r[5], wd4); r[4]=cadd(u,t); r[5]=csub(u,t); }
    { float2 u=r[6]; float2 t=cmulc(r[7], wd4); r[6]=cadd(u,t); r[7]=csub(u,t); }
    { float2 u=r[0]; float2 t=cmulc(r[2], wd2);         r[0]=cadd(u,t); r[2]=csub(u,t); }
    { float2 u=r[1]; float2 t=mul_pi(cmulc(r[3], wd2)); r[1]=cadd(u,t); r[3]=csub(u,t); }
    { float2 u=r[4]; float2 t=cmulc(r[6], wd2);         r[4]=cadd(u,t); r[6]=csub(u,t); }
    { float2 u=r[5]; float2 t=mul_pi(cmulc(r[7], wd2)); r[5]=cadd(u,t); r[7]=csub(u,t); }
    { float2 u=r[0]; float2 t=cmulc(r[4], wd);          r[0]=cadd(u,t); r[4]=csub(u,t); }
    { float2 u=r[1]; float2 t=cmulc(r[5], wc2);         r[1]=cadd(u,t); r[5]=csub(u,t); }
    { float2 u=r[2]; float2 t=mul_pi(cmulc(r[6], wd));  r[2]=cadd(u,t); r[6]=csub(u,t); }
    { float2 u=r[3]; float2 t=mul_pi(cmulc(r[7], wc2)); r[3]=cadd(u,t); r[7]=csub(u,t); }
}

// aligned pair access (positions p even; swz may flip parity, so select)
static __device__ __forceinline__ void readpair(const float2* cv, int p, float2& e0, float2& e1){
    int sp = swz(p);
    float4 q = *(const float4*)&cv[sp & ~1];
    float2 lo = f2(q.x,q.y), hi = f2(q.z,q.w);
    if (sp & 1) { e0 = hi; e1 = lo; } else { e0 = lo; e1 = hi; }
}
static __device__ __forceinline__ void writepair(float2* cv, int p, float2 e0, float2 e1){
    int sp = swz(p);
    float4 q;
    if (sp & 1) q = make_float4(e1.x,e1.y,e0.x,e0.y);
    else        q = make_float4(e0.x,e0.y,e1.x,e1.y);
    *(float4*)&cv[sp & ~1] = q;
}

static __device__ __forceinline__ float2 getw(const float2* T1, const float2* T2, int k){
    return cmul(T1[k>>6], T2[k&63]);   // e^{-i pi k / 8192}
}
static __device__ __forceinline__ float4 kpack(float2 Ck, float2 Cm, float2 w, float bds){
    const float s = 1.0f/16384.0f;
    float2 A  = f2(0.5f*(Ck.x+Cm.x), 0.5f*(Ck.y-Cm.y));
    float2 Bc = f2(0.5f*(Ck.x-Cm.x), 0.5f*(Ck.y+Cm.y));
    float2 B  = f2(Bc.y, -Bc.x);
    float2 wB = cmul(w, B);
    return make_float4((A.x+wB.x)*s + bds, (A.y+wB.y)*s,
                       (A.x-wB.x)*s + bds, -((A.y-wB.y)*s));
}
static __device__ __forceinline__ void pwmul(float2 Ck, float2 Cm, float4 Kp, float2 w,
                                             float2& Dk, float2& Dm){
    float2 A  = f2(0.5f*(Ck.x+Cm.x), 0.5f*(Ck.y-Cm.y));
    float2 Bc = f2(0.5f*(Ck.x-Cm.x), 0.5f*(Ck.y+Cm.y));
    float2 B  = f2(Bc.y, -Bc.x);
    float2 wB = cmul(w, B);
    float2 Xk = f2(A.x+wB.x, A.y+wB.y);
    float2 Xm = f2(A.x-wB.x, -(A.y-wB.y));
    float2 Yk = cmul(Xk, f2(Kp.x,Kp.y));
    float2 Ym = cmul(Xm, f2(Kp.z,Kp.w));
    float2 A2 = f2(Yk.x+Ym.x, Yk.y-Ym.y);
    float2 Bt = f2(Yk.x-Ym.x, Yk.y+Ym.y);
    float2 B2 = cmulc(Bt, w);
    Dk = f2(A2.x - B2.y, A2.y + B2.x);
    Dm = f2(A2.x + B2.y, B2.x - A2.y);
}

// LDS (f2): cv 8192 | tab 1024 | T1 64 | T2 64 | Kex 2 (+2 pad) = 9348 f2 = 74784 B
// -> 2 blocks/CU REAL (149568 <= 163840). K spectrum lives in registers (Ka/Kb, 32 VGPR);
// radix-8 passes (r[8], 2 groups/thread sequential) keep peak pressure ~110 < 128.
#define SMEM_BYTES (9348 * 8)

template<bool USE_K>
__global__ __launch_bounds__(NT, 2)
void hyena_conv(const float* __restrict__ h3g, const float* __restrict__ Wout,
                const float* __restrict__ krows,
                const float* __restrict__ x, const float* __restrict__ bias,
                float* __restrict__ out) {
    extern __shared__ float2 smem[];
    float2* cv  = smem;                 // 8192
    float2* tab = cv + 8192;            // 1024: e^{-i pi p/4096}
    float2* T1  = tab + 1024;           // 64:  e^{-i pi h/128}
    float2* T2  = T1 + 64;              // 64:  e^{-i pi l/8192}
    float2* Kex = T2 + 64;              // 2:   K-pack for f=2048 (lane-0 only)
    const int t = threadIdx.x;
    const int d = blockIdx.x;
    const float PI = 3.14159265358979323846f;

#pragma unroll
    for (int i = 0; i < 2; ++i) {
        int p = t + 512*i;
        float s_,c_; sincosf((PI/4096.0f)*(float)p, &s_, &c_); tab[p] = f2(c_, -s_);
    }
    if (t < 64)       { float s_,c_; sincosf((PI/128.0f)*(float)t, &s_,&c_); T1[t] = f2(c_,-s_); }
    else if (t < 128) { int l=t-64; float s_,c_; sincosf((PI/8192.0f)*(float)l,&s_,&c_); T2[l] = f2(c_,-s_); }
    __syncthreads();

    // shared base twiddles (same for both groups since 512 ≡ 0 mod 128/16/2)
    const float2 wdB = tab[(t&127)<<3];   // W_1024^(g&127)
    const float2 wdC = tab[(t&15)<<6];    // W_128^(g&15)
    const float2 wdD = tab[(t&1)<<9];     // W_16^(g&1)

    const float bds = bias[d] * (1.0f/16384.0f);

    float2 r[8];
    // ---- filter: pass A (stages 12..10) from source, 2 groups/thread ----
#pragma unroll 1
    for (int gi = 0; gi < 2; ++gi) {
        int g = t + 512*gi;
        if (USE_K) {
            const float2* kr = (const float2*)(krows + (size_t)d * SEQ_LEN);
#pragma unroll
            for (int k = 0; k < 4; ++k) r[k] = kr[g + 1024*k];
        } else {
            const float dmin = -3.0701134573253941f;
            const float dmax = -15.350567286626971f;
            const float absd = fabsf(dmin + (dmax - dmin) * ((float)d * (1.0f/1023.0f)));
#pragma unroll
            for (int k = 0; k < 4; ++k) {
                int e = g + 1024*k;
                const float4* h4 = (const float4*)(h3g + (size_t)(2*e)*16);
                float a0 = 0.f, a1 = 0.f;
#pragma unroll
                for (int v4 = 0; v4 < 4; ++v4) {
                    float4 q0 = h4[v4], q1 = h4[4+v4];
                    float w0 = Wout[(4*v4+0)*1024 + d], w1 = Wout[(4*v4+1)*1024 + d];
                    float w2 = Wout[(4*v4+2)*1024 + d], w3 = Wout[(4*v4+3)*1024 + d];
                    a0 += q0.x*w0 + q0.y*w1 + q0.z*w2 + q0.w*w3;
                    a1 += q1.x*w0 + q1.y*w1 + q1.z*w2 + q1.w*w3;
                }
                float ta = (float)(2*e)   * (1.0f/8191.0f);
                float tb = (float)(2*e+1) * (1.0f/8191.0f);
                r[k] = f2(a0 * __expf(-ta*absd), a1 * __expf(-tb*absd));
            }
        }
#pragma unroll
        for (int k = 4; k < 8; ++k) r[k] = f2(0.f, 0.f);
        dif3(r, tab[g]);
#pragma unroll
        for (int k = 0; k < 8; ++k) cv[swz(g + 1024*k)] = r[k];
    }
    __syncthreads();
    // pass B (stages 9..7)
#pragma unroll 1
    for (int gi = 0; gi < 2; ++gi) {
        int g = t + 512*gi;
        int base = ((g>>7)<<10) | (g&127);
#pragma unroll
        for (int k = 0; k < 8; ++k) r[k] = cv[swz(base + 128*k)];
        dif3(r, wdB);
#pragma unroll
        for (int k = 0; k < 8; ++k) cv[swz(base + 128*k)] = r[k];
    }
    __syncthreads();
    // pass C (stages 6..4)
#pragma unroll 1
    for (int gi = 0; gi < 2; ++gi) {
        int g = t + 512*gi;
        int base = ((g>>4)<<7) | (g&15);
#pragma unroll
        for (int k = 0; k < 8; ++k) r[k] = cv[swz(base + 16*k)];
        dif3(r, wdC);
#pragma unroll
        for (int k = 0; k < 8; ++k) cv[swz(base + 16*k)] = r[k];
    }
    __syncthreads();
    // pass D (stages 3..1)
#pragma unroll 1
    for (int gi = 0; gi < 2; ++gi) {
        int g = t + 512*gi;
        int base = ((g>>1)<<4) | (g&1);
#pragma unroll
        for (int k = 0; k < 8; ++k) r[k] = cv[swz(base + 2*k)];
        dif3(r, wdD);
#pragma unroll
        for (int k = 0; k < 8; ++k) cv[swz(base + 2*k)] = r[k];
    }
    __syncthreads();

    // ---- unpack rfft(K) into registers (q fully unrolled: static Ka/Kb indexing) ----
    float4 Ka[4], Kb[4];
#pragma unroll
    for (int q = 0; q < 4; ++q) {
        int f = t + 512*q;
        if (f == 0) {
            float2 a0,a1; readpair(cv, 0, a0, a1);
            float2 C0 = cadd(a0,a1), C4 = csub(a0,a1);   // fwd stage 0
            const float s = 1.0f/16384.0f;
            Ka[q] = make_float4((C0.x+C0.y)*s + bds, (C0.x-C0.y)*s + bds, C4.x*s + bds, -C4.y*s);
            Kb[q] = make_float4(0.f,0.f,0.f,0.f);
        } else {
            int g = 4096 - f;
            float2 a0,a1,b0,b1;
            readpair(cv, rev13(f), a0, a1);
            readpair(cv, rev13(g), b0, b1);
            float2 Cf=cadd(a0,a1), Cf4=csub(a0,a1), Cg=cadd(b0,b1), Cg4=csub(b0,b1);
            Ka[q] = kpack(Cf, Cg4, getw(T1,T2,f), bds);
            Kb[q] = kpack(Cg, Cf4, getw(T1,T2,g), bds);
        }
    }
    if (t == 0) {
        float2 b0,b1; readpair(cv, 2, b0, b1);   // rev13(2048) = 2
        float4 K20 = kpack(cadd(b0,b1), csub(b0,b1), getw(T1,T2,2048), bds);
        Kex[0] = f2(K20.x, K20.y);
        Kex[1] = f2(K20.z, K20.w);
    }
    __syncthreads();

    // ---- batches ----
#pragma unroll 1
    for (int b = 0; b < 4; ++b) {
        const float2* xr = (const float2*)(x + ((size_t)b*1024 + d)*SEQ_LEN);
        float2* yr = (float2*)(out + ((size_t)b*1024 + d)*SEQ_LEN);

        // F1: pass A from global
#pragma unroll 1
        for (int gi = 0; gi < 2; ++gi) {
            int g = t + 512*gi;
#pragma unroll
            for (int k = 0; k < 4; ++k) r[k] = xr[g + 1024*k];
#pragma unroll
            for (int k = 4; k < 8; ++k) r[k] = f2(0.f,0.f);
            dif3(r, tab[g]);
#pragma unroll
            for (int k = 0; k < 8; ++k) cv[swz(g + 1024*k)] = r[k];
        }
        __syncthreads();
        // F2: pass B
#pragma unroll 1
        for (int gi = 0; gi < 2; ++gi) {
            int g = t + 512*gi;
            int base = ((g>>7)<<10) | (g&127);
#pragma unroll
            for (int k = 0; k < 8; ++k) r[k] = cv[swz(base + 128*k)];
            dif3(r, wdB);
#pragma unroll
            for (int k = 0; k < 8; ++k) cv[swz(base + 128*k)] = r[k];
        }
        __syncthreads();
        // F3: pass C
#pragma unroll 1
        for (int gi = 0; gi < 2; ++gi) {
            int g = t + 512*gi;
            int base = ((g>>4)<<7) | (g&15);
#pragma unroll
            for (int k = 0; k < 8; ++k) r[k] = cv[swz(base + 16*k)];
            dif3(r, wdC);
#pragma unroll
            for (int k = 0; k < 8; ++k) cv[swz(base + 16*k)] = r[k];
        }
        __syncthreads();
        // F4: pass D
#pragma unroll 1
        for (int gi = 0; gi < 2; ++gi) {
            int g = t + 512*gi;
            int base = ((g>>1)<<4) | (g&1);
#pragma unroll
            for (int k = 0; k < 8; ++k) r[k] = cv[swz(base + 2*k)];
            dif3(r, wdD);
#pragma unroll
            for (int k = 0; k < 8; ++k) cv[swz(base + 2*k)] = r[k];
        }
        __syncthreads();

        // FUSED: fwd stage 0 + rfft-unpack * K + repack + inv stage 0 (q unrolled for Ka/Kb)
#pragma unroll
        for (int q = 0; q < 4; ++q) {
            int f = t + 512*q;
            if (f == 0) {
                float2 a0,a1; readpair(cv, 0, a0, a1);
                float2 C0 = cadd(a0,a1), C4 = csub(a0,a1);
                float R0 = C0.x + C0.y, RN = C0.x - C0.y;
                float Y0 = R0 * Ka[0].x, YN = RN * Ka[0].y;
                float2 D0 = f2(Y0+YN, Y0-YN);
                float2 Y4 = cmul(f2(C4.x,-C4.y), f2(Ka[0].z, Ka[0].w));
                float2 D4 = f2(2.f*Y4.x, -2.f*Y4.y);
                writepair(cv, 0, cadd(D0,D4), csub(D0,D4));
            } else {
                int g = 4096 - f;
                int p1 = rev13(f), p2 = rev13(g);
                float2 a0,a1,b0,b1;
                readpair(cv, p1, a0, a1);
                readpair(cv, p2, b0, b1);
                float2 Cf=cadd(a0,a1), Cf4=csub(a0,a1), Cg=cadd(b0,b1), Cg4=csub(b0,b1);
                float2 Df,Dg4,Dg,Df4;
                pwmul(Cf, Cg4, Ka[q], getw(T1,T2,f), Df, Dg4);
                pwmul(Cg, Cf4, Kb[q], getw(T1,T2,g), Dg, Df4);
                writepair(cv, p1, cadd(Df,Df4), csub(Df,Df4));
                writepair(cv, p2, cadd(Dg,Dg4), csub(Dg,Dg4));
            }
        }
        if (t == 0) {   // f = 2048 self-paired quad at positions (2,3)
            float4 K20 = make_float4(Kex[0].x, Kex[0].y, Kex[1].x, Kex[1].y);
            float2 b0,b1; readpair(cv, 2, b0, b1);
            float2 Ck=cadd(b0,b1), Cm=csub(b0,b1), Dk, Dm;
            pwmul(Ck, Cm, K20, getw(T1,T2,2048), Dk, Dm);
            writepair(cv, 2, cadd(Dk,Dm), csub(Dk,Dm));
        }
        __syncthreads();

        // I4: pass D' (stages 1..3)
#pragma unroll 1
        for (int gi = 0; gi < 2; ++gi) {
            int g = t + 512*gi;
            int base = ((g>>1)<<4) | (g&1);
#pragma unroll
            for (int k = 0; k < 8; ++k) r[k] = cv[swz(base + 2*k)];
            dit3(r, wdD);
#pragma unroll
            for (int k = 0; k < 8; ++k) cv[swz(base + 2*k)] = r[k];
        }
        __syncthreads();
        // I3: pass C' (stages 4..6)
#pragma unroll 1
        for (int gi = 0; gi < 2; ++gi) {
            int g = t + 512*gi;
            int base = ((g>>4)<<7) | (g&15);
#pragma unroll
            for (int k = 0; k < 8; ++k) r[k] = cv[swz(base + 16*k)];
            dit3(r, wdC);
#pragma unroll
            for (int k = 0; k < 8; ++k) cv[swz(base + 16*k)] = r[k];
        }
        __syncthreads();
        // I2: pass B' (stages 7..9)
#pragma unroll 1
        for (int gi = 0; gi < 2; ++gi) {
            int g = t + 512*gi;
            int base = ((g>>7)<<10) | (g&127);
#pragma unroll
            for (int k = 0; k < 8; ++k) r[k] = cv[swz(base + 128*k)];
            dit3(r, wdB);
#pragma unroll
            for (int k = 0; k < 8; ++k) cv[swz(base + 128*k)] = r[k];
        }
        __syncthreads();
        // I1: pass A' (stages 10..12), first half straight to global
#pragma unroll 1
        for (int gi = 0; gi < 2; ++gi) {
            int g = t + 512*gi;
#pragma unroll
            for (int k = 0; k < 8; ++k) r[k] = cv[swz(g + 1024*k)];
            dit3(r, tab[g]);
#pragma unroll
            for (int k = 0; k < 4; ++k) yr[g + 1024*k] = r[k];
        }
        __syncthreads();
    }
}

extern "C" void kernel_launch(void* const* d_in, const int* in_sizes, int n_in,
                              void* d_out, int out_size, void* d_ws, size_t ws_size,
                              hipStream_t stream) {
    const float* x    = (const float*)d_in[0];
    const float* z    = (const float*)d_in[2];
    const float* W1   = (const float*)d_in[3];
    const float* b1   = (const float*)d_in[4];
    const float* W2   = (const float*)d_in[5];
    const float* b2   = (const float*)d_in[6];
    const float* W3   = (const float*)d_in[7];
    const float* b3   = (const float*)d_in[8];
    const float* Wout = (const float*)d_in[9];
    const float* freq = (const float*)d_in[10];
    const float* bias = (const float*)d_in[11];
    float* out = (float*)d_out;
    float* h3  = (float*)d_ws;                                  // 512 KB
    float* krows = (float*)((char*)d_ws + 512*1024);            // 32 MB

    const size_t need = 512*1024 + (size_t)32*1024*1024;
    const bool use_k = ws_size >= need;

    hipLaunchKernelGGL(hyena_mlp, dim3(SEQ_LEN/256), dim3(256), 0, stream,
                       z, W1, b1, W2, b2, W3, b3, freq, h3);

    static bool attr_set = false;
    if (!attr_set) {
        (void)hipFuncSetAttribute((const void*)hyena_conv<true>,
                                  hipFuncAttributeMaxDynamicSharedMemorySize, SMEM_BYTES);
        (void)hipFuncSetAttribute((const void*)hyena_conv<false>,
                                  hipFuncAttributeMaxDynamicSharedMemorySize, SMEM_BYTES);
        attr_set = true;
    }

    if (use_k) {
        hipLaunchKernelGGL(hyena_proj, dim3(SEQ_LEN/PJ), dim3(256), 0, stream,
                           h3, Wout, krows);
        hipLaunchKernelGGL(hyena_conv<true>, dim3(1024), dim3(NT), SMEM_BYTES, stream,
                           h3, Wout, krows, x, bias, out);
    } else {
        hipLaunchKernelGGL(hyena_conv<false>, dim3(1024), dim3(NT), SMEM_BYTES, stream,
                           h3, Wout, krows, x, bias, out);
    }
}